// Round 4
// baseline (1519.799 us; speedup 1.0000x reference)
//
#include <hip/hip_runtime.h>
#include <utility>

#define H 20

// Raw v_rcp_f32 (~1 ulp); threshold is 1.9e-3, impact ~1e-7.
__device__ __forceinline__ float fast_rcp(float x) { return __builtin_amdgcn_rcpf(x); }
__device__ __forceinline__ float fsigmoid(float x) { return fast_rcp(1.0f + __expf(-x)); }
__device__ __forceinline__ float ftanh(float x) {
    float e = __expf(2.0f * x);
    return 1.0f - 2.0f * fast_rcp(e + 1.0f);
}

// Blocks LICM from hoisting weight s_loads across timesteps (R1-R3: hoist ->
// pressure explosion -> scratch). Re-issued s_loads hit K$/L2 - cheap.
#define LAUNDER(p) asm volatile("" : "+s"(p))

// ---------------------------------------------------------------------------
// All inner loops are C++17 fold expressions over std::index_sequence:
// every array index is a compile-time constant, so SROA promotion of the
// state arrays cannot be defeated by unroller thresholds. (R1-R3 evidence:
// identical ~450MB scratch traffic under 3 different occupancy directives ->
// arrays were living in scratch, not registers.)
// ---------------------------------------------------------------------------

template <int IN, size_t U, size_t... K>
__device__ __forceinline__ void dot4(const float* __restrict__ W, const float (&v)[IN],
                                     float& gi, float& gf, float& gg, float& go,
                                     std::index_sequence<K...>) {
    ((gi = fmaf(W[(0 * H + U) * IN + K], v[K], gi)), ...);
    ((gf = fmaf(W[(1 * H + U) * IN + K], v[K], gf)), ...);
    ((gg = fmaf(W[(2 * H + U) * IN + K], v[K], gg)), ...);
    ((go = fmaf(W[(3 * H + U) * IN + K], v[K], go)), ...);
}

template <int IN, size_t U>
__device__ __forceinline__ void cell_unit(const float* __restrict__ Wih,
                                          const float* __restrict__ Whh,
                                          const float* __restrict__ bias,
                                          const float (&x)[IN], const float (&h)[H],
                                          float (&c)[H], float (&hn)[H]) {
    float gi = bias[0 * H + U];
    float gf = bias[1 * H + U];
    float gg = bias[2 * H + U];
    float go = bias[3 * H + U];
    dot4<IN, U>(Wih, x, gi, gf, gg, go, std::make_index_sequence<IN>{});
    dot4<H, U>(Whh, h, gi, gf, gg, go, std::make_index_sequence<H>{});
    float cn = fsigmoid(gf) * c[U] + fsigmoid(gi) * ftanh(gg);
    c[U] = cn;
    hn[U] = fsigmoid(go) * ftanh(cn);
}

template <int IN, size_t... U>
__device__ __forceinline__ void cell_impl(const float* __restrict__ Wih,
                                          const float* __restrict__ Whh,
                                          const float* __restrict__ bias,
                                          const float (&x)[IN], float (&h)[H], float (&c)[H],
                                          std::index_sequence<U...>) {
    float hn[H];
    (cell_unit<IN, U>(Wih, Whh, bias, x, h, c, hn), ...);
    ((h[U] = hn[U]), ...);
}

template <int IN>
__device__ __forceinline__ void cell(const float* __restrict__ Wih,
                                     const float* __restrict__ Whh,
                                     const float* __restrict__ bias,
                                     const float (&x)[IN], float (&h)[H], float (&c)[H]) {
    cell_impl<IN>(Wih, Whh, bias, x, h, c, std::make_index_sequence<H>{});
}

template <size_t J, int LD, int NV, size_t... K>
__device__ __forceinline__ float mlp_dot(const float* __restrict__ W, const float (&v)[NV],
                                         float a, std::index_sequence<K...>) {
    ((a = fmaf(W[J * LD + K], v[K], a)), ...);
    return a;
}

template <size_t... J>
__device__ __forceinline__ void mlp_l1(const float* __restrict__ W, const float* __restrict__ b,
                                       const float (&h)[H], float (&z)[10], std::index_sequence<J...>) {
    ((z[J] = fmaxf(mlp_dot<J, H>(W, h, b[J], std::make_index_sequence<H>{}), 0.f)), ...);
}
template <size_t... J>
__device__ __forceinline__ void mlp_l2(const float* __restrict__ W, const float* __restrict__ b,
                                       const float (&z1)[10], float (&z2)[10], std::index_sequence<J...>) {
    ((z2[J] = fmaxf(mlp_dot<J, 10>(W, z1, b[J], std::make_index_sequence<10>{}), 0.f)), ...);
}

__global__ void __launch_bounds__(256) lstm_ar_kernel(
    const float* __restrict__ y_past, const float* __restrict__ x_past,
    const float* __restrict__ u_past, const float* __restrict__ s_past,
    const float* __restrict__ u_future,
    const float* __restrict__ Wih1_0, const float* __restrict__ Whh1_0, const float* __restrict__ b1_0,
    const float* __restrict__ Wih1_1, const float* __restrict__ Whh1_1, const float* __restrict__ b1_1,
    const float* __restrict__ Wih2_0, const float* __restrict__ Whh2_0, const float* __restrict__ b2_0,
    const float* __restrict__ Wih2_1, const float* __restrict__ Whh2_1, const float* __restrict__ b2_1,
    const float* __restrict__ fW1, const float* __restrict__ fb1,
    const float* __restrict__ fW2, const float* __restrict__ fb2,
    const float* __restrict__ fW3, const float* __restrict__ fb3,
    float* __restrict__ out, int B) {
    int b = blockIdx.x * blockDim.x + threadIdx.x;
    if (b >= B) return;

    float h0[H], c0[H], h1[H], c1[H];
    {
        auto zero = [&](auto... u) { ((h0[u] = 0.f, c0[u] = 0.f, h1[u] = 0.f, c1[u] = 0.f), ...); };
        zero(0,1,2,3,4,5,6,7,8,9,10,11,12,13,14,15,16,17,18,19);
    }

    // ---- encoder over lookback T=8 (input = concat[y,x,u,s] = 16 feats) ----
    for (int t = 0; t < 8; ++t) {
        LAUNDER(Wih1_0); LAUNDER(Whh1_0); LAUNDER(b1_0);
        LAUNDER(Wih1_1); LAUNDER(Whh1_1); LAUNDER(b1_1);
        float x[16];
        x[0] = y_past[b * 8 + t];
        {   // x_past row: 8 contiguous floats -> two float4 loads
            const float4* p = (const float4*)(x_past + (size_t)(b * 8 + t) * 8);
            float4 a0 = p[0], a1 = p[1];
            x[1] = a0.x; x[2] = a0.y; x[3] = a0.z; x[4] = a0.w;
            x[5] = a1.x; x[6] = a1.y; x[7] = a1.z; x[8] = a1.w;
        }
        {   // u_past row: 4 contiguous floats
            const float4* p = (const float4*)(u_past + (size_t)(b * 8 + t) * 4);
            float4 a0 = p[0];
            x[9] = a0.x; x[10] = a0.y; x[11] = a0.z; x[12] = a0.w;
        }
        {   // s_past row: 3 floats
            const float* p = s_past + (size_t)(b * 8 + t) * 3;
            x[13] = p[0]; x[14] = p[1]; x[15] = p[2];
        }
        cell<16>(Wih1_0, Whh1_0, b1_0, x, h0, c0);
        cell<H>(Wih1_1, Whh1_1, b1_1, h0, h1, c1);
    }

    // ---- decoder over lookahead T=4 (input = u_future, 4 feats) + MLP head ----
    for (int t = 0; t < 4; ++t) {
        LAUNDER(Wih2_0); LAUNDER(Whh2_0); LAUNDER(b2_0);
        LAUNDER(Wih2_1); LAUNDER(Whh2_1); LAUNDER(b2_1);
        LAUNDER(fW1); LAUNDER(fb1); LAUNDER(fW2); LAUNDER(fb2); LAUNDER(fW3); LAUNDER(fb3);
        float x[4];
        {
            const float4* p = (const float4*)(u_future + (size_t)(b * 4 + t) * 4);
            float4 a0 = p[0];
            x[0] = a0.x; x[1] = a0.y; x[2] = a0.z; x[3] = a0.w;
        }
        cell<4>(Wih2_0, Whh2_0, b2_0, x, h0, c0);
        cell<H>(Wih2_1, Whh2_1, b2_1, h0, h1, c1);

        // FCNN 20 -> 10 -> 10 -> 1
        float z1[10], z2[10];
        mlp_l1(fW1, fb1, h1, z1, std::make_index_sequence<10>{});
        mlp_l2(fW2, fb2, z1, z2, std::make_index_sequence<10>{});
        float o = mlp_dot<0, 10>(fW3, z2, fb3[0], std::make_index_sequence<10>{});
        out[b * 4 + t] = o;
    }
}

extern "C" void kernel_launch(void* const* d_in, const int* in_sizes, int n_in,
                              void* d_out, int out_size, void* d_ws, size_t ws_size,
                              hipStream_t stream) {
    (void)n_in; (void)d_ws; (void)ws_size;
    const float* y_past   = (const float*)d_in[0];
    const float* x_past   = (const float*)d_in[1];
    const float* u_past   = (const float*)d_in[2];
    const float* s_past   = (const float*)d_in[3];
    const float* u_future = (const float*)d_in[4];
    const float* Wih1_0 = (const float*)d_in[5];
    const float* Whh1_0 = (const float*)d_in[6];
    const float* b1_0   = (const float*)d_in[7];
    const float* Wih1_1 = (const float*)d_in[8];
    const float* Whh1_1 = (const float*)d_in[9];
    const float* b1_1   = (const float*)d_in[10];
    const float* Wih2_0 = (const float*)d_in[11];
    const float* Whh2_0 = (const float*)d_in[12];
    const float* b2_0   = (const float*)d_in[13];
    const float* Wih2_1 = (const float*)d_in[14];
    const float* Whh2_1 = (const float*)d_in[15];
    const float* b2_1   = (const float*)d_in[16];
    const float* fW1 = (const float*)d_in[17];
    const float* fb1 = (const float*)d_in[18];
    const float* fW2 = (const float*)d_in[19];
    const float* fb2 = (const float*)d_in[20];
    const float* fW3 = (const float*)d_in[21];
    const float* fb3 = (const float*)d_in[22];
    float* out = (float*)d_out;

    int B = in_sizes[0] / 8;  // y_past is [B,8,1]
    (void)out_size;

    dim3 block(256);
    dim3 grid((B + 255) / 256);
    lstm_ar_kernel<<<grid, block, 0, stream>>>(
        y_past, x_past, u_past, s_past, u_future,
        Wih1_0, Whh1_0, b1_0, Wih1_1, Whh1_1, b1_1,
        Wih2_0, Whh2_0, b2_0, Wih2_1, Whh2_1, b2_1,
        fW1, fb1, fW2, fb2, fW3, fb3, out, B);
}